// Round 12
// baseline (185.135 us; speedup 1.0000x reference)
//
#include <hip/hip_runtime.h>
#include <math.h>

// GraphAttentionBlock: B=1, N=4096, E=256, H=8, D=32, fp32 in/out.
// R12: R11 + (a) conflict-free attn LDS: Ks[64][44] / Vs[32][76] (row strides
// 88B/152B, == 2 mod 4 dwords) with all staging writes + fragment reads as
// b64 pairs -- the R5/R8-proven zero-conflict config (R11's b128-from-16B-
// granular-strides produced 8-way quad conflicts, 5.2e6 cycles);
// (b) out_mfma grid (64,8): 512 blocks, 2/CU latency hiding.

#define NTOK 4096
#define EDIM 256
#define HEADS 8
#define HD 32
#define NSPLIT 2
#define QSCALE 0.17677669529663687f            // 1/sqrt(32)
#define CINIT (-8.0f)                          // exp shift, folded into MFMA C

typedef __attribute__((ext_vector_type(8))) short bf16x8;
typedef __attribute__((ext_vector_type(4))) float f32x4;
typedef __attribute__((ext_vector_type(4))) unsigned long long u64x4;

struct uu2 { uint2 a, b; };

static __device__ inline short f2bf(float f) {          // RNE
    unsigned u = __float_as_uint(f);
    u = (u + 0x7FFFu + ((u >> 16) & 1u)) >> 16;
    return (short)u;
}
// truncating bf16x2 pack: one v_perm_b32 (hi16 of a -> lo, hi16 of b -> hi)
static __device__ inline unsigned packtrunc(float a, float b) {
    return __builtin_amdgcn_perm(__float_as_uint(b), __float_as_uint(a),
                                 0x07060302u);
}
// p = (mask bit for this lane) ? v : 0   -- one VALU op, sgpr-pair mask
static __device__ inline float sel_mask(float v, unsigned long long m) {
    float r;
    asm("v_cndmask_b32 %0, 0, %1, %2" : "=v"(r) : "v"(v), "s"(m));
    return r;
}
// load a 16B MFMA fragment from LDS as two b64s (conflict-free strides)
static __device__ inline bf16x8 ld_frag(const short* p) {
    uu2 u;
    u.a = *(const uint2*)p;
    u.b = *(const uint2*)(p + 4);
    return __builtin_bit_cast(bf16x8, u);
}

// ---- prep: adjacency -> S^T bitmask (blocks 0..16383) + bf16 casts -------
// maskT[qb*1024+kt*16+b*4+j] bit l = adj[qb*16+(l&15)][kt*64+b*16+((l>>4)&3)*4+j]
__global__ __launch_bounds__(256) void prep(
    const int* __restrict__ adj, unsigned long long* __restrict__ maskT,
    const float* __restrict__ x,  const float* __restrict__ Wq,
    const float* __restrict__ Wk, const float* __restrict__ Wv,
    const float* __restrict__ Wo,
    short* __restrict__ xb,  short* __restrict__ wqb,
    short* __restrict__ wkb, short* __restrict__ wvb,
    short* __restrict__ wob)
{
    const int bid = blockIdx.x;
    if (bid < 16384) {
        const int w = bid * 4 + (threadIdx.x >> 6);  // (qb,kt,b)
        const int l = threadIdx.x & 63;
        const int qb = w >> 8;
        const int kt = (w >> 2) & 63;
        const int b = w & 3;
        const int row = qb * 16 + (l & 15);
        const int col = kt * 64 + b * 16 + ((l >> 4) & 3) * 4;
        const int4 av = *(const int4*)&adj[row * NTOK + col];
        const unsigned long long m0 = __ballot(av.x != 0);
        const unsigned long long m1 = __ballot(av.y != 0);
        const unsigned long long m2 = __ballot(av.z != 0);
        const unsigned long long m3 = __ballot(av.w != 0);
        if (l == 0) {
            unsigned long long* dst = &maskT[(size_t)w * 4];
            dst[0] = m0; dst[1] = m1; dst[2] = m2; dst[3] = m3;
        }
    } else {
        const int gid = (bid - 16384) * 256 + threadIdx.x;
        const int e = gid * 4;
        const float* src; short* dst; int off;
        if (e < NTOK * EDIM) { src = x; dst = xb; off = e; }
        else {
            const int r = e - NTOK * EDIM;
            const int wsel = r >> 16;
            off = r & 65535;
            src = (wsel == 0) ? Wq : (wsel == 1) ? Wk : (wsel == 2) ? Wv : Wo;
            dst = (wsel == 0) ? wqb : (wsel == 1) ? wkb : (wsel == 2) ? wvb : wob;
        }
        float4 v = *(const float4*)&src[off];
        uint2 t;
        t.x = (unsigned short)f2bf(v.x) | ((unsigned)(unsigned short)f2bf(v.y) << 16);
        t.y = (unsigned short)f2bf(v.z) | ((unsigned)(unsigned short)f2bf(v.w) << 16);
        *(uint2*)&dst[off] = t;
    }
}

// ---- QKV projection via MFMA, 16x64 per wave; q/k head-major, v transposed
__global__ __launch_bounds__(256) void qkv_mfma(
    const short* __restrict__ xb,
    const short* __restrict__ Wqb, const short* __restrict__ Wkb,
    const short* __restrict__ Wvb,
    const float* __restrict__ bq, const float* __restrict__ bk,
    const float* __restrict__ bv,
    short* __restrict__ qo, short* __restrict__ ko, short* __restrict__ vto)
{
    const int tid = threadIdx.x;
    const int wv = tid >> 6, lane = tid & 63;
    const int grp = lane >> 4, lcol = lane & 15;
    const int wsel = blockIdx.y >> 2;                  // 0=Q 1=K 2=V
    const int n0 = (blockIdx.y & 3) << 6;
    const int m0 = blockIdx.x * 64 + wv * 16;
    const short* __restrict__ W = (wsel == 0) ? Wqb : (wsel == 1) ? Wkb : Wvb;
    const float* __restrict__ bias = (wsel == 0) ? bq : (wsel == 1) ? bk : bv;

    bf16x8 af[8];
#pragma unroll
    for (int k = 0; k < 8; ++k)
        af[k] = *(const bf16x8*)&xb[(m0 + lcol) * 256 + k * 32 + grp * 8];

    f32x4 acc[4] = {};
#pragma unroll
    for (int k = 0; k < 8; ++k) {
#pragma unroll
        for (int t = 0; t < 4; ++t) {
            const bf16x8 bt =
                *(const bf16x8*)&W[(n0 + t * 16 + lcol) * 256 + k * 32 + grp * 8];
            acc[t] = __builtin_amdgcn_mfma_f32_16x16x32_bf16(af[k], bt, acc[t], 0, 0, 0);
        }
    }
#pragma unroll
    for (int t = 0; t < 4; ++t) {
        const int feat = n0 + t * 16 + lcol;
        const float bval = bias[feat];
        const int h = feat >> 5, d = feat & 31;
        if (wsel == 2) {
            uint2 o;
            o.x = (unsigned short)f2bf(acc[t][0] + bval) |
                  ((unsigned)(unsigned short)f2bf(acc[t][1] + bval) << 16);
            o.y = (unsigned short)f2bf(acc[t][2] + bval) |
                  ((unsigned)(unsigned short)f2bf(acc[t][3] + bval) << 16);
            *(uint2*)&vto[h * (HD * NTOK) + d * NTOK + m0 + grp * 4] = o;
        } else {
            short* __restrict__ out = (wsel == 0) ? qo : ko;
            const float sc = (wsel == 0) ? QSCALE : 1.0f;  // 1/sqrt(D) into Q
#pragma unroll
            for (int j = 0; j < 4; ++j)
                out[h * (NTOK * HD) + (m0 + grp * 4 + j) * HD + d] =
                    f2bf((acc[t][j] + bval) * sc);
        }
    }
}

// ---- MFMA flash attention: block-shared K/V LDS staging, dbuf, 1 barrier -
__global__ __launch_bounds__(256) void attn_mfma(
    const short* __restrict__ qg, const short* __restrict__ kg,
    const short* __restrict__ vtg, const unsigned long long* __restrict__ maskT,
    float* __restrict__ o_part, float* __restrict__ l_part)
{
    const int h = blockIdx.y;
    const int split = blockIdx.z;
    const int q0 = blockIdx.x << 6;
    const short* __restrict__ Q  = qg  + h * (NTOK * HD);
    const short* __restrict__ K  = kg  + h * (NTOK * HD);
    const short* __restrict__ Vt = vtg + h * (HD * NTOK);

    __shared__ short Ks[2][64][44];      // 88B rows (22 dw): <=2-way on b64
    __shared__ short Vs[2][32][76];      // 152B rows (38 dw): <=2-way on b64
    __shared__ short P_lds[4][16][76];   // 152B rows (proven zero-conflict)

    const int tid = threadIdx.x;
    const int wv = tid >> 6;
    const int lane = tid & 63;
    const int grp = lane >> 4;
    const int lcol = lane & 15;
    const int q0w = q0 + wv * 16;

    // staging coords: thread tid stages K chunk (krow, kc8) and V chunk
    const int krow = tid >> 2, kc8 = (tid & 3) << 3;    // K: 64 rows x 64B
    const int vrow = tid >> 3, vc8 = (tid & 7) << 3;    // Vt: 32 rows x 128B

    // Q as B-operand: B[n=lcol(qrow)][k=grp*8+j(d)]
    const bf16x8 qfrag = *(const bf16x8*)&Q[(q0w + lcol) * HD + grp * 8];

    const int qb = __builtin_amdgcn_readfirstlane(blockIdx.x * 4 + wv);
    const unsigned long long* __restrict__ mbase = maskT + (size_t)qb * 1024;

    f32x4 ot[2] = {};     // O^T C-layout: row=grp*4+j (d), col=lcol (qrow)
    float lsum = 0.f;

    const int kt_begin = split * (64 / NSPLIT);
    const int kt_end = kt_begin + (64 / NSPLIT);

    // preload first tile into buffer 0 (b64 halves: 16B-granular strides
    // would break b128 alignment and re-create quad conflicts)
    {
        const int k0 = kt_begin << 6;
        const int4 kr = *(const int4*)&K[(k0 + krow) * HD + kc8];
        const int4 vr = *(const int4*)&Vt[vrow * NTOK + k0 + vc8];
        uint2 t;
        t.x = kr.x; t.y = kr.y; *(uint2*)&Ks[0][krow][kc8] = t;
        t.x = kr.z; t.y = kr.w; *(uint2*)&Ks[0][krow][kc8 + 4] = t;
        t.x = vr.x; t.y = vr.y; *(uint2*)&Vs[0][vrow][vc8] = t;
        t.x = vr.z; t.y = vr.w; *(uint2*)&Vs[0][vrow][vc8 + 4] = t;
    }
    __syncthreads();

    int cur = 0;
    for (int kt = kt_begin; kt < kt_end; ++kt) {
        // issue next tile's global loads first (full tile to cover latency)
        int4 kr, vr;
        const bool has_next = (kt + 1 < kt_end);
        if (has_next) {
            const int k0n = (kt + 1) << 6;
            kr = *(const int4*)&K[(k0n + krow) * HD + kc8];
            vr = *(const int4*)&Vt[vrow * NTOK + k0n + vc8];
        }

        // mask words for this tile (contiguous scalar region)
        const u64x4* mp = (const u64x4*)(mbase + kt * 16);
        const u64x4 wa = mp[0], wb = mp[1], wc = mp[2], wd = mp[3];

        // fragments from shared LDS tiles (b64 pairs, conflict-free)
        bf16x8 kf[4], vf[4];
#pragma unroll
        for (int b = 0; b < 4; ++b)
            kf[b] = ld_frag(&Ks[cur][b * 16 + lcol][grp * 8]);
#pragma unroll
        for (int c = 0; c < 2; ++c) {
            vf[c * 2 + 0] = ld_frag(&Vs[cur][c * 16 + lcol][grp * 8]);
            vf[c * 2 + 1] = ld_frag(&Vs[cur][c * 16 + lcol][32 + grp * 8]);
        }

        // S^T = K Q^T - 8: row=key_in_blk, col=qrow
        f32x4 s[4];
#pragma unroll
        for (int b = 0; b < 4; ++b)
            s[b] = __builtin_amdgcn_mfma_f32_16x16x32_bf16(
                kf[b], qfrag, (f32x4){CINIT, CINIT, CINIT, CINIT}, 0, 0, 0);

        // p = exp(s) masked; truncating v_perm pack; ds_write_b64
#pragma unroll
        for (int b = 0; b < 4; ++b) {
            const u64x4 wj = (b == 0) ? wa : (b == 1) ? wb : (b == 2) ? wc : wd;
            const float p0 = sel_mask(__expf(s[b][0]), wj[0]);
            const float p1 = sel_mask(__expf(s[b][1]), wj[1]);
            const float p2 = sel_mask(__expf(s[b][2]), wj[2]);
            const float p3 = sel_mask(__expf(s[b][3]), wj[3]);
            lsum += (p0 + p1) + (p2 + p3);
            uint2 t;
            t.x = packtrunc(p0, p1);
            t.y = packtrunc(p2, p3);
            *(uint2*)&P_lds[wv][lcol][b * 16 + grp * 4] = t;
        }

        // P as B-operand: row-contiguous b64 pairs
        const bf16x8 pf0 = ld_frag(&P_lds[wv][lcol][grp * 8]);
        const bf16x8 pf1 = ld_frag(&P_lds[wv][lcol][32 + grp * 8]);

#pragma unroll
        for (int c = 0; c < 2; ++c) {
            ot[c] = __builtin_amdgcn_mfma_f32_16x16x32_bf16(vf[c * 2 + 0], pf0, ot[c], 0, 0, 0);
            ot[c] = __builtin_amdgcn_mfma_f32_16x16x32_bf16(vf[c * 2 + 1], pf1, ot[c], 0, 0, 0);
        }

        // stage next tile into the other buffer, then one barrier
        if (has_next) {
            uint2 t;
            t.x = kr.x; t.y = kr.y; *(uint2*)&Ks[cur ^ 1][krow][kc8] = t;
            t.x = kr.z; t.y = kr.w; *(uint2*)&Ks[cur ^ 1][krow][kc8 + 4] = t;
            t.x = vr.x; t.y = vr.y; *(uint2*)&Vs[cur ^ 1][vrow][vc8] = t;
            t.x = vr.z; t.y = vr.w; *(uint2*)&Vs[cur ^ 1][vrow][vc8 + 4] = t;
        }
        __syncthreads();
        cur ^= 1;
    }

    // l: sum over the 4 lane-groups holding this qrow's keys
    lsum += __shfl_xor(lsum, 16);
    lsum += __shfl_xor(lsum, 32);

    float* __restrict__ ob = o_part + split * (NTOK * EDIM);
#pragma unroll
    for (int c = 0; c < 2; ++c) {
        float4 st;
        st.x = ot[c][0]; st.y = ot[c][1]; st.z = ot[c][2]; st.w = ot[c][3];
        *(float4*)&ob[(q0w + lcol) * EDIM + h * HD + c * 16 + grp * 4] = st;
    }
    if (grp == 0)
        l_part[split * (NTOK * HEADS) + (q0w + lcol) * HEADS + h] = lsum;
}

// ---- output projection, combine fused: Y = ((Σo)/(Σl)) @ Wo^T + bo -------
__global__ __launch_bounds__(256) void out_mfma(
    const float* __restrict__ o_part, const float* __restrict__ l_part,
    const short* __restrict__ Wob, const float* __restrict__ bo,
    float* __restrict__ Y)
{
    const int tid = threadIdx.x;
    const int wv = tid >> 6, lane = tid & 63;
    const int grp = lane >> 4, lcol = lane & 15;
    const int n0 = blockIdx.y << 5;          // 32-wide n tiles, 512 blocks
    const int m0 = blockIdx.x * 64 + wv * 16;
    const int r = m0 + lcol;

    bf16x8 af[8];
#pragma unroll
    for (int k = 0; k < 8; ++k) {
        float4 s0 = {0.f, 0.f, 0.f, 0.f}, s1 = {0.f, 0.f, 0.f, 0.f};
        float lv = 0.f;
#pragma unroll
        for (int s = 0; s < NSPLIT; ++s) {
            const float* op = &o_part[s * (NTOK * EDIM) + r * EDIM + k * 32 + grp * 8];
            const float4 t0 = *(const float4*)op;
            const float4 t1 = *(const float4*)(op + 4);
            s0.x += t0.x; s0.y += t0.y; s0.z += t0.z; s0.w += t0.w;
            s1.x += t1.x; s1.y += t1.y; s1.z += t1.z; s1.w += t1.w;
            lv += l_part[s * (NTOK * HEADS) + r * HEADS + k];
        }
        const float inv = 1.0f / lv;
        bf16x8 t;
        t[0] = f2bf(s0.x * inv); t[1] = f2bf(s0.y * inv);
        t[2] = f2bf(s0.z * inv); t[3] = f2bf(s0.w * inv);
        t[4] = f2bf(s1.x * inv); t[5] = f2bf(s1.y * inv);
        t[6] = f2bf(s1.z * inv); t[7] = f2bf(s1.w * inv);
        af[k] = t;
    }

    f32x4 acc[2] = {};
#pragma unroll
    for (int k = 0; k < 8; ++k) {
#pragma unroll
        for (int t = 0; t < 2; ++t) {
            const bf16x8 bt =
                *(const bf16x8*)&Wob[(n0 + t * 16 + lcol) * 256 + k * 32 + grp * 8];
            acc[t] = __builtin_amdgcn_mfma_f32_16x16x32_bf16(af[k], bt, acc[t], 0, 0, 0);
        }
    }
#pragma unroll
    for (int t = 0; t < 2; ++t) {
        const float bval = bo[n0 + t * 16 + lcol];
#pragma unroll
        for (int j = 0; j < 4; ++j)
            Y[(m0 + grp * 4 + j) * EDIM + n0 + t * 16 + lcol] = acc[t][j] + bval;
    }
}

extern "C" void kernel_launch(void* const* d_in, const int* in_sizes, int n_in,
                              void* d_out, int out_size, void* d_ws, size_t ws_size,
                              hipStream_t stream) {
    (void)in_sizes; (void)n_in; (void)out_size; (void)ws_size;
    const float* x  = (const float*)d_in[0];
    const int*  adj = (const int*)d_in[1];
    const float* Wq = (const float*)d_in[2];
    const float* bq = (const float*)d_in[3];
    const float* Wk = (const float*)d_in[4];
    const float* bk = (const float*)d_in[5];
    const float* Wv = (const float*)d_in[6];
    const float* bv = (const float*)d_in[7];
    const float* Wo = (const float*)d_in[8];
    const float* bo = (const float*)d_in[9];

    char* ws = (char*)d_ws;
    short* x_bf  = (short*)(ws);                        // 2 MB  [N][256]
    short* q_ws  = (short*)(ws + (2u << 20));           // 2 MB  [H][N][32]
    short* k_ws  = (short*)(ws + (4u << 20));           // 2 MB
    short* vt_ws = (short*)(ws + (6u << 20));           // 2 MB  [H][32][N]
    unsigned long long* maskT =
        (unsigned long long*)(ws + (8u << 20));         // 2 MB
    short* Wq_bf = (short*)(ws + (10u << 20));          // 128 KB each
    short* Wk_bf = Wq_bf + (EDIM * EDIM);
    short* Wv_bf = Wk_bf + (EDIM * EDIM);
    short* Wo_bf = Wv_bf + (EDIM * EDIM);
    float* l_part = (float*)(ws + (11u << 20));         // 256 KB [2][N][8]
    float* o_part = (float*)(ws + (12u << 20));         // 8 MB   [2][N][256]

    prep<<<dim3(16384 + 1280), 256, 0, stream>>>(
        adj, maskT, x, Wq, Wk, Wv, Wo, x_bf, Wq_bf, Wk_bf, Wv_bf, Wo_bf);
    qkv_mfma<<<dim3(64, 12), 256, 0, stream>>>(x_bf, Wq_bf, Wk_bf, Wv_bf,
                                               bq, bk, bv, q_ws, k_ws, vt_ws);
    attn_mfma<<<dim3(64, HEADS, NSPLIT), 256, 0, stream>>>(
        q_ws, k_ws, vt_ws, maskT, o_part, l_part);
    out_mfma<<<dim3(64, 8), 256, 0, stream>>>(o_part, l_part, Wo_bf, bo,
                                              (float*)d_out);
}

// Round 13
// 178.875 us; speedup vs baseline: 1.0350x; 1.0350x over previous
//
#include <hip/hip_runtime.h>
#include <math.h>

// GraphAttentionBlock: B=1, N=4096, E=256, H=8, D=32, fp32 in/out.
// R13: R11 attn body (b128 LDS staging -- R12's b64 split traded conflicts
// for 2x LDS issue, net loss) + exp2 fold (log2e into Q scale, -8*log2e into
// MFMA C-init, __builtin_amdgcn_exp2f = compiler-visible v_exp_f32; kills
// 16 v_mul/tile). out_mfma reverted to (64,4) (R12's (64,8) doubled the
// duplicate combine traffic). 4 launches.

#define NTOK 4096
#define EDIM 256
#define HEADS 8
#define HD 32
#define NSPLIT 2
#define QSCALE 0.17677669529663687f            // 1/sqrt(32)
#define LOG2E 1.4426950408889634f
#define CINIT (-11.541560327111707f)           // -8 * log2(e)

typedef __attribute__((ext_vector_type(8))) short bf16x8;
typedef __attribute__((ext_vector_type(4))) float f32x4;
typedef __attribute__((ext_vector_type(4))) unsigned long long u64x4;

static __device__ inline short f2bf(float f) {          // RNE
    unsigned u = __float_as_uint(f);
    u = (u + 0x7FFFu + ((u >> 16) & 1u)) >> 16;
    return (short)u;
}
// truncating bf16x2 pack: one v_perm_b32 (hi16 of a -> lo, hi16 of b -> hi)
static __device__ inline unsigned packtrunc(float a, float b) {
    return __builtin_amdgcn_perm(__float_as_uint(b), __float_as_uint(a),
                                 0x07060302u);
}
// p = (mask bit for this lane) ? v : 0   -- one VALU op, sgpr-pair mask
static __device__ inline float sel_mask(float v, unsigned long long m) {
    float r;
    asm("v_cndmask_b32 %0, 0, %1, %2" : "=v"(r) : "v"(v), "s"(m));
    return r;
}

// ---- prep: adjacency -> S^T bitmask (blocks 0..16383) + bf16 casts -------
// maskT[qb*1024+kt*16+b*4+j] bit l = adj[qb*16+(l&15)][kt*64+b*16+((l>>4)&3)*4+j]
__global__ __launch_bounds__(256) void prep(
    const int* __restrict__ adj, unsigned long long* __restrict__ maskT,
    const float* __restrict__ x,  const float* __restrict__ Wq,
    const float* __restrict__ Wk, const float* __restrict__ Wv,
    const float* __restrict__ Wo,
    short* __restrict__ xb,  short* __restrict__ wqb,
    short* __restrict__ wkb, short* __restrict__ wvb,
    short* __restrict__ wob)
{
    const int bid = blockIdx.x;
    if (bid < 16384) {
        const int w = bid * 4 + (threadIdx.x >> 6);  // (qb,kt,b)
        const int l = threadIdx.x & 63;
        const int qb = w >> 8;
        const int kt = (w >> 2) & 63;
        const int b = w & 3;
        const int row = qb * 16 + (l & 15);
        const int col = kt * 64 + b * 16 + ((l >> 4) & 3) * 4;
        const int4 av = *(const int4*)&adj[row * NTOK + col];
        const unsigned long long m0 = __ballot(av.x != 0);
        const unsigned long long m1 = __ballot(av.y != 0);
        const unsigned long long m2 = __ballot(av.z != 0);
        const unsigned long long m3 = __ballot(av.w != 0);
        if (l == 0) {
            unsigned long long* dst = &maskT[(size_t)w * 4];
            dst[0] = m0; dst[1] = m1; dst[2] = m2; dst[3] = m3;
        }
    } else {
        const int gid = (bid - 16384) * 256 + threadIdx.x;
        const int e = gid * 4;
        const float* src; short* dst; int off;
        if (e < NTOK * EDIM) { src = x; dst = xb; off = e; }
        else {
            const int r = e - NTOK * EDIM;
            const int wsel = r >> 16;
            off = r & 65535;
            src = (wsel == 0) ? Wq : (wsel == 1) ? Wk : (wsel == 2) ? Wv : Wo;
            dst = (wsel == 0) ? wqb : (wsel == 1) ? wkb : (wsel == 2) ? wvb : wob;
        }
        float4 v = *(const float4*)&src[off];
        uint2 t;
        t.x = (unsigned short)f2bf(v.x) | ((unsigned)(unsigned short)f2bf(v.y) << 16);
        t.y = (unsigned short)f2bf(v.z) | ((unsigned)(unsigned short)f2bf(v.w) << 16);
        *(uint2*)&dst[off] = t;
    }
}

// ---- QKV projection via MFMA, 16x64 per wave; q/k head-major, v transposed
__global__ __launch_bounds__(256) void qkv_mfma(
    const short* __restrict__ xb,
    const short* __restrict__ Wqb, const short* __restrict__ Wkb,
    const short* __restrict__ Wvb,
    const float* __restrict__ bq, const float* __restrict__ bk,
    const float* __restrict__ bv,
    short* __restrict__ qo, short* __restrict__ ko, short* __restrict__ vto)
{
    const int tid = threadIdx.x;
    const int wv = tid >> 6, lane = tid & 63;
    const int grp = lane >> 4, lcol = lane & 15;
    const int wsel = blockIdx.y >> 2;                  // 0=Q 1=K 2=V
    const int n0 = (blockIdx.y & 3) << 6;
    const int m0 = blockIdx.x * 64 + wv * 16;
    const short* __restrict__ W = (wsel == 0) ? Wqb : (wsel == 1) ? Wkb : Wvb;
    const float* __restrict__ bias = (wsel == 0) ? bq : (wsel == 1) ? bk : bv;

    bf16x8 af[8];
#pragma unroll
    for (int k = 0; k < 8; ++k)
        af[k] = *(const bf16x8*)&xb[(m0 + lcol) * 256 + k * 32 + grp * 8];

    f32x4 acc[4] = {};
#pragma unroll
    for (int k = 0; k < 8; ++k) {
#pragma unroll
        for (int t = 0; t < 4; ++t) {
            const bf16x8 bt =
                *(const bf16x8*)&W[(n0 + t * 16 + lcol) * 256 + k * 32 + grp * 8];
            acc[t] = __builtin_amdgcn_mfma_f32_16x16x32_bf16(af[k], bt, acc[t], 0, 0, 0);
        }
    }
#pragma unroll
    for (int t = 0; t < 4; ++t) {
        const int feat = n0 + t * 16 + lcol;
        const float bval = bias[feat];
        const int h = feat >> 5, d = feat & 31;
        if (wsel == 2) {
            uint2 o;
            o.x = (unsigned short)f2bf(acc[t][0] + bval) |
                  ((unsigned)(unsigned short)f2bf(acc[t][1] + bval) << 16);
            o.y = (unsigned short)f2bf(acc[t][2] + bval) |
                  ((unsigned)(unsigned short)f2bf(acc[t][3] + bval) << 16);
            *(uint2*)&vto[h * (HD * NTOK) + d * NTOK + m0 + grp * 4] = o;
        } else {
            short* __restrict__ out = (wsel == 0) ? qo : ko;
            // fold 1/sqrt(D) * log2(e) into Q so attn uses raw exp2
            const float sc = (wsel == 0) ? (QSCALE * LOG2E) : 1.0f;
#pragma unroll
            for (int j = 0; j < 4; ++j)
                out[h * (NTOK * HD) + (m0 + grp * 4 + j) * HD + d] =
                    f2bf((acc[t][j] + bval) * sc);
        }
    }
}

// ---- MFMA flash attention: block-shared K/V LDS staging, dbuf, 1 barrier -
__global__ __launch_bounds__(256) void attn_mfma(
    const short* __restrict__ qg, const short* __restrict__ kg,
    const short* __restrict__ vtg, const unsigned long long* __restrict__ maskT,
    float* __restrict__ o_part, float* __restrict__ l_part)
{
    const int h = blockIdx.y;
    const int split = blockIdx.z;
    const int q0 = blockIdx.x << 6;
    const short* __restrict__ Q  = qg  + h * (NTOK * HD);
    const short* __restrict__ K  = kg  + h * (NTOK * HD);
    const short* __restrict__ Vt = vtg + h * (HD * NTOK);

    __shared__ short Ks[2][64][40];      // 80B rows
    __shared__ short Vs[2][32][72];      // 144B rows
    __shared__ short P_lds[4][16][76];   // 152B rows (wave-private)

    const int tid = threadIdx.x;
    const int wv = tid >> 6;
    const int lane = tid & 63;
    const int grp = lane >> 4;
    const int lcol = lane & 15;
    const int q0w = q0 + wv * 16;

    // staging coords: thread tid stages K chunk (krow, kc8) and V chunk
    const int krow = tid >> 2, kc8 = (tid & 3) << 3;    // K: 64 rows x 64B
    const int vrow = tid >> 3, vc8 = (tid & 7) << 3;    // Vt: 32 rows x 128B

    // Q as B-operand: B[n=lcol(qrow)][k=grp*8+j(d)]
    const bf16x8 qfrag = *(const bf16x8*)&Q[(q0w + lcol) * HD + grp * 8];

    const int qb = __builtin_amdgcn_readfirstlane(blockIdx.x * 4 + wv);
    const unsigned long long* __restrict__ mbase = maskT + (size_t)qb * 1024;

    f32x4 ot[2] = {};     // O^T C-layout: row=grp*4+j (d), col=lcol (qrow)
    float lsum = 0.f;

    const int kt_begin = split * (64 / NSPLIT);
    const int kt_end = kt_begin + (64 / NSPLIT);

    // preload first tile into buffer 0
    {
        const int k0 = kt_begin << 6;
        const int4 kr = *(const int4*)&K[(k0 + krow) * HD + kc8];
        const int4 vr = *(const int4*)&Vt[vrow * NTOK + k0 + vc8];
        *(int4*)&Ks[0][krow][kc8] = kr;
        *(int4*)&Vs[0][vrow][vc8] = vr;
    }
    __syncthreads();

    int cur = 0;
    for (int kt = kt_begin; kt < kt_end; ++kt) {
        // issue next tile's global loads first (full tile to cover latency)
        int4 kr, vr;
        const bool has_next = (kt + 1 < kt_end);
        if (has_next) {
            const int k0n = (kt + 1) << 6;
            kr = *(const int4*)&K[(k0n + krow) * HD + kc8];
            vr = *(const int4*)&Vt[vrow * NTOK + k0n + vc8];
        }

        // mask words for this tile (contiguous scalar region)
        const u64x4* mp = (const u64x4*)(mbase + kt * 16);
        const u64x4 wa = mp[0], wb = mp[1], wc = mp[2], wd = mp[3];

        // fragments from shared LDS tiles
        bf16x8 kf[4], vf[4];
#pragma unroll
        for (int b = 0; b < 4; ++b)
            kf[b] = *(const bf16x8*)&Ks[cur][b * 16 + lcol][grp * 8];
#pragma unroll
        for (int c = 0; c < 2; ++c) {
            vf[c * 2 + 0] = *(const bf16x8*)&Vs[cur][c * 16 + lcol][grp * 8];
            vf[c * 2 + 1] = *(const bf16x8*)&Vs[cur][c * 16 + lcol][32 + grp * 8];
        }

        // S^T = K Q^T - 8*log2e: row=key_in_blk, col=qrow (log2-domain)
        f32x4 s[4];
#pragma unroll
        for (int b = 0; b < 4; ++b)
            s[b] = __builtin_amdgcn_mfma_f32_16x16x32_bf16(
                kf[b], qfrag, (f32x4){CINIT, CINIT, CINIT, CINIT}, 0, 0, 0);

        // p = exp2(s) masked; truncating v_perm pack; ds_write_b64
#pragma unroll
        for (int b = 0; b < 4; ++b) {
            const u64x4 wj = (b == 0) ? wa : (b == 1) ? wb : (b == 2) ? wc : wd;
            const float p0 = sel_mask(__builtin_amdgcn_exp2f(s[b][0]), wj[0]);
            const float p1 = sel_mask(__builtin_amdgcn_exp2f(s[b][1]), wj[1]);
            const float p2 = sel_mask(__builtin_amdgcn_exp2f(s[b][2]), wj[2]);
            const float p3 = sel_mask(__builtin_amdgcn_exp2f(s[b][3]), wj[3]);
            lsum += (p0 + p1) + (p2 + p3);
            uint2 t;
            t.x = packtrunc(p0, p1);
            t.y = packtrunc(p2, p3);
            *(uint2*)&P_lds[wv][lcol][b * 16 + grp * 4] = t;
        }

        // P as B-operand: row-contiguous b64 pairs
        const uint2 pl0 = *(const uint2*)&P_lds[wv][lcol][grp * 8];
        const uint2 pl1 = *(const uint2*)&P_lds[wv][lcol][grp * 8 + 4];
        const uint2 pl2 = *(const uint2*)&P_lds[wv][lcol][32 + grp * 8];
        const uint2 pl3 = *(const uint2*)&P_lds[wv][lcol][32 + grp * 8 + 4];
        struct { uint2 a, b; } u0 = {pl0, pl1}, u1 = {pl2, pl3};
        const bf16x8 pf0 = __builtin_bit_cast(bf16x8, u0);
        const bf16x8 pf1 = __builtin_bit_cast(bf16x8, u1);

#pragma unroll
        for (int c = 0; c < 2; ++c) {
            ot[c] = __builtin_amdgcn_mfma_f32_16x16x32_bf16(vf[c * 2 + 0], pf0, ot[c], 0, 0, 0);
            ot[c] = __builtin_amdgcn_mfma_f32_16x16x32_bf16(vf[c * 2 + 1], pf1, ot[c], 0, 0, 0);
        }

        // stage next tile into the other buffer, then one barrier
        if (has_next) {
            *(int4*)&Ks[cur ^ 1][krow][kc8] = kr;
            *(int4*)&Vs[cur ^ 1][vrow][vc8] = vr;
        }
        __syncthreads();
        cur ^= 1;
    }

    // l: sum over the 4 lane-groups holding this qrow's keys
    lsum += __shfl_xor(lsum, 16);
    lsum += __shfl_xor(lsum, 32);

    float* __restrict__ ob = o_part + split * (NTOK * EDIM);
#pragma unroll
    for (int c = 0; c < 2; ++c) {
        float4 st;
        st.x = ot[c][0]; st.y = ot[c][1]; st.z = ot[c][2]; st.w = ot[c][3];
        *(float4*)&ob[(q0w + lcol) * EDIM + h * HD + c * 16 + grp * 4] = st;
    }
    if (grp == 0)
        l_part[split * (NTOK * HEADS) + (q0w + lcol) * HEADS + h] = lsum;
}

// ---- output projection, combine fused: Y = ((Σo)/(Σl)) @ Wo^T + bo -------
__global__ __launch_bounds__(256) void out_mfma(
    const float* __restrict__ o_part, const float* __restrict__ l_part,
    const short* __restrict__ Wob, const float* __restrict__ bo,
    float* __restrict__ Y)
{
    const int tid = threadIdx.x;
    const int wv = tid >> 6, lane = tid & 63;
    const int grp = lane >> 4, lcol = lane & 15;
    const int n0 = blockIdx.y << 6;
    const int m0 = blockIdx.x * 64 + wv * 16;
    const int r = m0 + lcol;

    bf16x8 af[8];
#pragma unroll
    for (int k = 0; k < 8; ++k) {
        float4 s0 = {0.f, 0.f, 0.f, 0.f}, s1 = {0.f, 0.f, 0.f, 0.f};
        float lv = 0.f;
#pragma unroll
        for (int s = 0; s < NSPLIT; ++s) {
            const float* op = &o_part[s * (NTOK * EDIM) + r * EDIM + k * 32 + grp * 8];
            const float4 t0 = *(const float4*)op;
            const float4 t1 = *(const float4*)(op + 4);
            s0.x += t0.x; s0.y += t0.y; s0.z += t0.z; s0.w += t0.w;
            s1.x += t1.x; s1.y += t1.y; s1.z += t1.z; s1.w += t1.w;
            lv += l_part[s * (NTOK * HEADS) + r * HEADS + k];
        }
        const float inv = 1.0f / lv;
        bf16x8 t;
        t[0] = f2bf(s0.x * inv); t[1] = f2bf(s0.y * inv);
        t[2] = f2bf(s0.z * inv); t[3] = f2bf(s0.w * inv);
        t[4] = f2bf(s1.x * inv); t[5] = f2bf(s1.y * inv);
        t[6] = f2bf(s1.z * inv); t[7] = f2bf(s1.w * inv);
        af[k] = t;
    }

    f32x4 acc[4] = {};
#pragma unroll
    for (int k = 0; k < 8; ++k) {
#pragma unroll
        for (int t = 0; t < 4; ++t) {
            const bf16x8 bt =
                *(const bf16x8*)&Wob[(n0 + t * 16 + lcol) * 256 + k * 32 + grp * 8];
            acc[t] = __builtin_amdgcn_mfma_f32_16x16x32_bf16(af[k], bt, acc[t], 0, 0, 0);
        }
    }
#pragma unroll
    for (int t = 0; t < 4; ++t) {
        const float bval = bo[n0 + t * 16 + lcol];
#pragma unroll
        for (int j = 0; j < 4; ++j)
            Y[(m0 + grp * 4 + j) * EDIM + n0 + t * 16 + lcol] = acc[t][j] + bval;
    }
}

extern "C" void kernel_launch(void* const* d_in, const int* in_sizes, int n_in,
                              void* d_out, int out_size, void* d_ws, size_t ws_size,
                              hipStream_t stream) {
    (void)in_sizes; (void)n_in; (void)out_size; (void)ws_size;
    const float* x  = (const float*)d_in[0];
    const int*  adj = (const int*)d_in[1];
    const float* Wq = (const float*)d_in[2];
    const float* bq = (const float*)d_in[3];
    const float* Wk = (const float*)d_in[4];
    const float* bk = (const float*)d_in[5];
    const float* Wv = (const float*)d_in[6];
    const float* bv = (const float*)d_in[7];
    const float* Wo = (const float*)d_in[8];
    const float* bo = (const float*)d_in[9];

    char* ws = (char*)d_ws;
    short* x_bf  = (short*)(ws);                        // 2 MB  [N][256]
    short* q_ws  = (short*)(ws + (2u << 20));           // 2 MB  [H][N][32]
    short* k_ws  = (short*)(ws + (4u << 20));           // 2 MB
    short* vt_ws = (short*)(ws + (6u << 20));           // 2 MB  [H][32][N]
    unsigned long long* maskT =
        (unsigned long long*)(ws + (8u << 20));         // 2 MB
    short* Wq_bf = (short*)(ws + (10u << 20));          // 128 KB each
    short* Wk_bf = Wq_bf + (EDIM * EDIM);
    short* Wv_bf = Wk_bf + (EDIM * EDIM);
    short* Wo_bf = Wv_bf + (EDIM * EDIM);
    float* l_part = (float*)(ws + (11u << 20));         // 256 KB [2][N][8]
    float* o_part = (float*)(ws + (12u << 20));         // 8 MB   [2][N][256]

    prep<<<dim3(16384 + 1280), 256, 0, stream>>>(
        adj, maskT, x, Wq, Wk, Wv, Wo, x_bf, Wq_bf, Wk_bf, Wv_bf, Wo_bf);
    qkv_mfma<<<dim3(64, 12), 256, 0, stream>>>(x_bf, Wq_bf, Wk_bf, Wv_bf,
                                               bq, bk, bv, q_ws, k_ws, vt_ws);
    attn_mfma<<<dim3(64, HEADS, NSPLIT), 256, 0, stream>>>(
        q_ws, k_ws, vt_ws, maskT, o_part, l_part);
    out_mfma<<<dim3(64, 4), 256, 0, stream>>>(o_part, l_part, Wo_bf, bo,
                                              (float*)d_out);
}